// Round 3
// baseline (388.561 us; speedup 1.0000x reference)
//
#include <hip/hip_runtime.h>
#include <math.h>

#define NHEADS 16
#define HDIM   64
#define HID    1024
#define BATCH  2
#define SEQ    2048
#define NX (BATCH*SEQ*HID)       // 4194304
#define NW (HID*HID)             // 1048576

typedef unsigned short u16;
typedef __attribute__((ext_vector_type(8))) short  bf16x8;   // 8 bf16 = 4 VGPR
typedef __attribute__((ext_vector_type(8))) unsigned short u16x8;
typedef __attribute__((ext_vector_type(4))) float  f32x4;

// ---------------------------------------------------------------------------
// Fragment-tiled layout ("FT"): operand rows r, inner dim k. Subtile =
// 16 rows x 32 k. Element (r,k) lives at
//   ((r>>4)*KB + (k>>5))*512 + ((k>>3)&3)*128 + (r&15)*8 + (k&7)     [u16]
// (KB = k-blocks per row-block row). A wave's MFMA fragment load
// (lane = quad*16+lx -> 16B) is then 64 lanes x 16B CONTIGUOUS: perfectly
// coalesced global_load_dwordx4, no LDS round-trip needed.
// hi / lo planes are separate arrays (keeps lane stride 16B).
// ---------------------------------------------------------------------------

__device__ __forceinline__ void split8(const float* xf, bf16x8& hi, bf16x8& lo) {
#pragma unroll
    for (int j = 0; j < 8; j++) {
        unsigned u = __float_as_uint(xf[j]);
        hi[j] = (short)(u >> 16);
        float hf = __uint_as_float(u & 0xFFFF0000u);
        lo[j] = (short)(__float_as_uint(xf[j] - hf) >> 16);
    }
}
__device__ __forceinline__ void split1(float v, u16& h, u16& l) {
    unsigned u = __float_as_uint(v);
    h = (u16)(u >> 16);
    l = (u16)(__float_as_uint(v - __uint_as_float(u & 0xFFFF0000u)) >> 16);
}

// ---------------------------------------------------------------------------
// RoPE tables
// ---------------------------------------------------------------------------
__global__ void rope_tables_kernel(float* __restrict__ ct, float* __restrict__ st) {
    int idx = blockIdx.x * 256 + threadIdx.x;
    if (idx >= SEQ * HDIM) return;
    int s  = idx >> 6;
    int dh = idx & 63;
    int i  = dh & 31;
    float inv = exp2f(-(float)i * (13.28771237954945f / 32.0f));  // log2(10000)/32
    float fr  = (float)s * inv;
    ct[idx] = cosf(fr);
    st[idx] = sinf(fr);
}

// ---------------------------------------------------------------------------
// Pre-pass: split X and W0/1/2 fp32 -> bf16 hi/lo planes, FRAG-TILED (KB=32).
// ---------------------------------------------------------------------------
__global__ void split_kernel(const float* __restrict__ X,
                             const float* __restrict__ W0,
                             const float* __restrict__ W1,
                             const float* __restrict__ W2,
                             u16* __restrict__ Xhi, u16* __restrict__ Xlo,
                             u16* __restrict__ Whi, u16* __restrict__ Wlo)
{
    long idx = ((long)blockIdx.x * 256 + threadIdx.x) * 4;
    if (idx >= (long)NX + 3L * NW) return;
    const float* src; u16* dh; u16* dl; long off;
    if (idx < NX) { src = X; dh = Xhi; dl = Xlo; off = idx; }
    else {
        long rr = idx - NX;
        int wi = (int)(rr >> 20);
        off = rr & (NW - 1);
        src = (wi == 0) ? W0 : ((wi == 1) ? W1 : W2);
        dh = Whi + (size_t)wi * NW;
        dl = Wlo + (size_t)wi * NW;
    }
    const int r = (int)(off >> 10);
    const int k = (int)(off & 1023);
    // frag-tiled offset (KB=32):
    const size_t fo = ((size_t)(r >> 4) * 32 + (k >> 5)) * 512
                    + (size_t)((k >> 3) & 3) * 128 + (size_t)(r & 15) * 8 + (k & 7);
    float4 v = *(const float4*)(src + off);
    const float* vf = (const float*)&v;
    ushort4 h4, l4;
    u16* hp = (u16*)&h4; u16* lp = (u16*)&l4;
#pragma unroll
    for (int e = 0; e < 4; e++) split1(vf[e], hp[e], lp[e]);
    *(ushort4*)(dh + fo) = h4;
    *(ushort4*)(dl + fo) = l4;
}

// ---------------------------------------------------------------------------
// MFMA QKV GEMM, NO LDS / NO BARRIERS in the K-loop: fragments loaded
// directly from frag-tiled global (L1/L2-hot), register double-buffered.
// 128x128 block, 4 waves x 64x64, split-bf16 3-term emulation.
// Outputs (all frag-tiled, hi/lo planes, per (b,head) base = (b*16+h)*S*D):
//   proj 0: Q (RoPE, pre-scaled by log2(e)/8)  rows=s, k=dh, KB=2
//   proj 1: K (RoPE)  rows=s, k=dh, KB=2
//   proj 2: V^T       rows=d, k=s,  KB=64  (via LDS transpose in epilogue)
// ---------------------------------------------------------------------------
__global__ __launch_bounds__(256, 2) void qkv_mfma_kernel(
    const u16* __restrict__ Xhi, const u16* __restrict__ Xlo,
    const u16* __restrict__ Whi, const u16* __restrict__ Wlo,
    const float* __restrict__ ct, const float* __restrict__ st,
    u16* __restrict__ Qhi, u16* __restrict__ Qlo,
    u16* __restrict__ Khi, u16* __restrict__ Klo,
    u16* __restrict__ Vhi, u16* __restrict__ Vlo)
{
    __shared__ unsigned vtr[64][129];   // proj-2 transpose buffer only

    const int t    = threadIdx.x;
    const int lane = t & 63;
    const int w    = t >> 6;
    const int lx   = lane & 15;
    const int quad = lane >> 4;
    const int proj = blockIdx.z;
    const int n0   = blockIdx.x * 128;
    const int m0   = blockIdx.y * 128;

    const u16* __restrict__ Wph = Whi + (size_t)proj * NW;
    const u16* __restrict__ Wpl = Wlo + (size_t)proj * NW;

    const int am = (w & 1) * 64;
    const int bn = (w >> 1) * 64;
    const int lp = quad * 128 + lx * 8;        // lane part of frag offset

    const u16 *pAh[4], *pAl[4], *pBh[4], *pBl[4];
#pragma unroll
    for (int i = 0; i < 4; i++) {
        const size_t o = ((size_t)(((m0 + am) >> 4) + i) * 32) * 512 + lp;
        pAh[i] = Xhi + o; pAl[i] = Xlo + o;
    }
#pragma unroll
    for (int j = 0; j < 4; j++) {
        const size_t o = ((size_t)(((n0 + bn) >> 4) + j) * 32) * 512 + lp;
        pBh[j] = Wph + o; pBl[j] = Wpl + o;
    }

    f32x4 acc[4][4];
#pragma unroll
    for (int i = 0; i < 4; i++)
#pragma unroll
        for (int j = 0; j < 4; j++) acc[i][j] = (f32x4){0.f, 0.f, 0.f, 0.f};

    // prefetch k-block 0
    bf16x8 cah[4], cal[4], cbh[4], cbl[4];
#pragma unroll
    for (int i = 0; i < 4; i++) { cah[i] = *(const bf16x8*)(pAh[i]); cal[i] = *(const bf16x8*)(pAl[i]); }
#pragma unroll
    for (int j = 0; j < 4; j++) { cbh[j] = *(const bf16x8*)(pBh[j]); cbl[j] = *(const bf16x8*)(pBl[j]); }

#pragma unroll 1
    for (int kt = 0; kt < HID; kt += 32) {
        const int ko = (kt + 32 < HID) ? ((kt + 32) >> 5) * 512 : 0;
        bf16x8 nah[4], nal[4], nbh[4], nbl[4];
#pragma unroll
        for (int i = 0; i < 4; i++) { nah[i] = *(const bf16x8*)(pAh[i] + ko); nal[i] = *(const bf16x8*)(pAl[i] + ko); }
#pragma unroll
        for (int j = 0; j < 4; j++) { nbh[j] = *(const bf16x8*)(pBh[j] + ko); nbl[j] = *(const bf16x8*)(pBl[j] + ko); }

#pragma unroll
        for (int j = 0; j < 4; j++)
#pragma unroll
            for (int i = 0; i < 4; i++) {
                acc[i][j] = __builtin_amdgcn_mfma_f32_16x16x32_bf16(cah[i], cbh[j], acc[i][j], 0, 0, 0);
                acc[i][j] = __builtin_amdgcn_mfma_f32_16x16x32_bf16(cal[i], cbh[j], acc[i][j], 0, 0, 0);
                acc[i][j] = __builtin_amdgcn_mfma_f32_16x16x32_bf16(cah[i], cbl[j], acc[i][j], 0, 0, 0);
            }
#pragma unroll
        for (int i = 0; i < 4; i++) { cah[i] = nah[i]; cal[i] = nal[i]; }
#pragma unroll
        for (int j = 0; j < 4; j++) { cbh[j] = nbh[j]; cbl[j] = nbl[j]; }
    }

    // ---- epilogue ----
    const int b      = m0 >> 11;
    const int head   = (n0 >> 6) + (w >> 1);
    const int m_base = m0 + am;

    if (proj < 2) {
        // RoPE in registers: partner dh^32 = acc[i][j^2], same lane.
#pragma unroll
        for (int i = 0; i < 4; i++) {
#pragma unroll
            for (int r = 0; r < 4; r++) {
                const int s = (m_base + i * 16 + quad * 4 + r) & 2047;
                const float* ctr = ct + s * HDIM;
                const float* str = st + s * HDIM;
                float nv[4];
#pragma unroll
                for (int j = 0; j < 4; j++) {
                    const int dh = j * 16 + lx;
                    const float c  = ctr[dh];
                    const float sn = str[dh];
                    const float x  = acc[i][j][r];
                    const float p  = acc[i][j ^ 2][r];
                    nv[j] = (j < 2) ? (x * c - p * sn) : (x * c + p * sn);
                }
#pragma unroll
                for (int j = 0; j < 4; j++) acc[i][j][r] = nv[j];
            }
        }
        // store Q or K, frag-tiled (rows=s, k=dh, KB=2)
        // Q additionally pre-scaled by log2(e)/8 so attn can exp2 directly.
        u16* dh_ = (proj == 0) ? Qhi : Khi;
        u16* dl_ = (proj == 0) ? Qlo : Klo;
        const float qscale = (proj == 0) ? 0.18033688011112042f : 1.0f;
        const size_t obase = (size_t)(b * NHEADS + head) * SEQ * HDIM;
#pragma unroll
        for (int i = 0; i < 4; i++)
#pragma unroll
            for (int r = 0; r < 4; r++) {
                const int s   = (m_base + i * 16 + quad * 4 + r) & 2047;
                const int rb  = s >> 4;
                const int lxq = s & 15;
#pragma unroll
                for (int j = 0; j < 4; j++) {
                    const size_t fo = obase + ((size_t)rb * 2 + (j >> 1)) * 512
                                    + (size_t)((j & 1) * 2 + (lx >> 3)) * 128
                                    + (size_t)lxq * 8 + (lx & 7);
                    u16 hh, ll;
                    split1(acc[i][j][r] * qscale, hh, ll);
                    dh_[fo] = hh;
                    dl_[fo] = ll;
                }
            }
    } else {
        // V: two-pass LDS transpose -> frag-tiled V^T (rows=d, k=s, KB=64)
#pragma unroll 1
        for (int pass = 0; pass < 2; pass++) {
            __syncthreads();
            if ((w & 1) == pass) {
#pragma unroll
                for (int i = 0; i < 4; i++)
#pragma unroll
                    for (int j = 0; j < 4; j++)
#pragma unroll
                        for (int r = 0; r < 4; r++) {
                            const int ml = i * 16 + quad * 4 + r;
                            const int nl = bn + j * 16 + lx;
                            const float v = acc[i][j][r];
                            unsigned u  = __float_as_uint(v);
                            unsigned hi = u & 0xFFFF0000u;
                            unsigned lo = __float_as_uint(v - __uint_as_float(hi)) >> 16;
                            vtr[ml][nl] = hi | lo;
                        }
            }
            __syncthreads();
            {
                const int d      = t >> 1;            // 0..127 (2 heads x 64)
                const int sh     = (t & 1) * 32;
                const int headv  = (n0 >> 6) + (d >> 6);
                const int dd     = d & 63;
                const size_t vbase = (size_t)(b * NHEADS + headv) * SEQ * HDIM;
                const int s0base = (m0 & 2047) + pass * 64 + sh;
#pragma unroll
                for (int k = 0; k < 4; k++) {
                    const int s0 = s0base + k * 8;
                    u16x8 hv, lv;
#pragma unroll
                    for (int e = 0; e < 8; e++) {
                        unsigned u = vtr[sh + k * 8 + e][d];
                        hv[e] = (u16)(u >> 16);
                        lv[e] = (u16)(u & 0xFFFFu);
                    }
                    const size_t fo = vbase + ((size_t)(dd >> 4) * 64 + (s0 >> 5)) * 512
                                    + (size_t)((s0 >> 3) & 3) * 128 + (size_t)(dd & 15) * 8;
                    *(u16x8*)(Vhi + fo) = hv;
                    *(u16x8*)(Vlo + fo) = lv;
                }
            }
        }
    }
}

// ---------------------------------------------------------------------------
// Flash attention, NO LDS for K/V (frag-tiled global loads), NO barriers in
// the tile loop. P round-trips per-wave LDS (wave-internal, lgkmcnt only).
// v4: kv-SPLIT: blockIdx.x = (q-tile)*2 + kv-half. Each block processes 128 q
// rows over 1024 kv positions -> grid 1024 = 4 blocks/CU (VGPR 128, LDS 35KB
// both permit 4). Softmax has no running max, so halves are additive: store
// unnormalized O-partial (f32) + l-partial; combine_kernel finishes.
// Register pipeline (V early, K prefetch to alternate buffer) as v3.
// Q arrives pre-scaled by log2(e)/8, so scores feed exp2 directly.
// ---------------------------------------------------------------------------
__global__ __launch_bounds__(256, 2) void attn_kernel(
    const u16* __restrict__ Qhi, const u16* __restrict__ Qlo,
    const u16* __restrict__ Khi, const u16* __restrict__ Klo,
    const u16* __restrict__ Vhi, const u16* __restrict__ Vlo,
    float* __restrict__ OP, float* __restrict__ LP)
{
    __shared__ float PS[4][32][68];
    __shared__ float lsh[128];

    const int t    = threadIdx.x;
    const int lane = t & 63;
    const int w    = t >> 6;
    const int lx   = lane & 15;
    const int quad = lane >> 4;

    const int q0  = (blockIdx.x >> 1) * 128;
    const int kvh = blockIdx.x & 1;
    const int kt0 = kvh * (SEQ / 2);
    const int h  = blockIdx.y;
    const int b  = blockIdx.z;
    const size_t base = (size_t)(b * NHEADS + h) * SEQ * HDIM;
    const int lp = quad * 128 + lx * 8;

    // Q fragments (already split + pre-scaled in workspace)
    bf16x8 qh[2][2], ql[2][2];
#pragma unroll
    for (int a = 0; a < 2; a++)
#pragma unroll
        for (int ks = 0; ks < 2; ks++) {
            const size_t fo = base + ((size_t)((q0 >> 4) + w * 2 + a) * 2 + ks) * 512 + lp;
            qh[a][ks] = *(const bf16x8*)(Qhi + fo);
            ql[a][ks] = *(const bf16x8*)(Qlo + fo);
        }

    f32x4 O[2][4];
    float l_part[2][4];
#pragma unroll
    for (int a = 0; a < 2; a++) {
#pragma unroll
        for (int dt = 0; dt < 4; dt++) O[a][dt] = (f32x4){0.f,0.f,0.f,0.f};
#pragma unroll
        for (int r = 0; r < 4; r++) l_part[a][r] = 0.f;
    }

    // K double-buffer (A/B), prologue fills A with tile kt0
    bf16x8 kAh[2][4], kAl[2][4], kBh[2][4], kBl[2][4];
#pragma unroll
    for (int c = 0; c < 4; c++)
#pragma unroll
        for (int ks = 0; ks < 2; ks++) {
            const size_t fo = base + ((size_t)((kt0 >> 4) + c) * 2 + ks) * 512 + lp;
            kAh[ks][c] = *(const bf16x8*)(Khi + fo);
            kAl[ks][c] = *(const bf16x8*)(Klo + fo);
        }

    // one kv-tile: consume (ckh,ckl) for tile kt, prefetch tile ktn into (nkh,nkl)
    auto tile_body = [&](bf16x8 (&ckh)[2][4], bf16x8 (&ckl)[2][4],
                         bf16x8 (&nkh)[2][4], bf16x8 (&nkl)[2][4],
                         int kt, int ktn) {
        // ---- V fragment loads (issued first; consumed after QK+exp) ----
        bf16x8 vh[2][4], vl[2][4];
#pragma unroll
        for (int dt = 0; dt < 4; dt++)
#pragma unroll
            for (int ks2 = 0; ks2 < 2; ks2++) {
                const size_t fo = base + ((size_t)dt * 64 + (kt >> 5) + ks2) * 512 + lp;
                vh[ks2][dt] = *(const bf16x8*)(Vhi + fo);
                vl[ks2][dt] = *(const bf16x8*)(Vlo + fo);
            }

        // ---- scores + exp -> PS (frees current K registers) ----
#pragma unroll
        for (int a = 0; a < 2; a++) {
#pragma unroll
            for (int c = 0; c < 4; c++) {
                f32x4 acc = (f32x4){0.f,0.f,0.f,0.f};
#pragma unroll
                for (int ks = 0; ks < 2; ks++) {
                    acc = __builtin_amdgcn_mfma_f32_16x16x32_bf16(qh[a][ks], ckh[ks][c], acc, 0, 0, 0);
                    acc = __builtin_amdgcn_mfma_f32_16x16x32_bf16(ql[a][ks], ckh[ks][c], acc, 0, 0, 0);
                    acc = __builtin_amdgcn_mfma_f32_16x16x32_bf16(qh[a][ks], ckl[ks][c], acc, 0, 0, 0);
                }
#pragma unroll
                for (int r = 0; r < 4; r++) {
                    float p = exp2f(acc[r]);           // Q pre-scaled: 2^(qk*log2e/8)
                    l_part[a][r] += p;
                    PS[w][a * 16 + quad * 4 + r][c * 16 + lx] = p;
                }
            }
        }

        // ---- prefetch next tile's K into alternate buffer ----
#pragma unroll
        for (int c = 0; c < 4; c++)
#pragma unroll
            for (int ks = 0; ks < 2; ks++) {
                const size_t fo = base + ((size_t)((ktn >> 4) + c) * 2 + ks) * 512 + lp;
                nkh[ks][c] = *(const bf16x8*)(Khi + fo);
                nkl[ks][c] = *(const bf16x8*)(Klo + fo);
            }

        // ---- PV ----
#pragma unroll
        for (int a = 0; a < 2; a++) {
#pragma unroll
            for (int ks2 = 0; ks2 < 2; ks2++) {
                const float* ps = &PS[w][a * 16 + lx][ks2 * 32 + quad * 8];
                float pf[8];
                *(float4*)&pf[0] = *(const float4*)ps;
                *(float4*)&pf[4] = *(const float4*)(ps + 4);
                bf16x8 phi, plo;
                split8(pf, phi, plo);
#pragma unroll
                for (int dt = 0; dt < 4; dt++) {
                    O[a][dt] = __builtin_amdgcn_mfma_f32_16x16x32_bf16(phi, vh[ks2][dt], O[a][dt], 0, 0, 0);
                    O[a][dt] = __builtin_amdgcn_mfma_f32_16x16x32_bf16(plo, vh[ks2][dt], O[a][dt], 0, 0, 0);
                    O[a][dt] = __builtin_amdgcn_mfma_f32_16x16x32_bf16(phi, vl[ks2][dt], O[a][dt], 0, 0, 0);
                }
            }
        }
    };

#pragma unroll 1
    for (int kt = kt0; kt < kt0 + SEQ / 2; kt += 128) {
        tile_body(kAh, kAl, kBh, kBl, kt,      kt + 64);
        tile_body(kBh, kBl, kAh, kAl, kt + 64, kt0 + ((kt + 128 - kt0) & (SEQ / 2 - 1)));
    }

    float lred[2][4];
#pragma unroll
    for (int a = 0; a < 2; a++)
#pragma unroll
        for (int r = 0; r < 4; r++) {
            float l = l_part[a][r];
            l += __shfl_xor(l, 1);
            l += __shfl_xor(l, 2);
            l += __shfl_xor(l, 4);
            l += __shfl_xor(l, 8);
            lred[a][r] = l;
        }

    // stage UNNORMALIZED O in PS (reused as [128][68]), l into lsh
    float* Po = &PS[0][0][0];
    __syncthreads();            // all waves done with their PS regions
#pragma unroll
    for (int a = 0; a < 2; a++) {
#pragma unroll
        for (int dt = 0; dt < 4; dt++)
#pragma unroll
            for (int r = 0; r < 4; r++)
                Po[(size_t)(w * 32 + a * 16 + quad * 4 + r) * 68 + dt * 16 + lx] =
                    O[a][dt][r];
#pragma unroll
        for (int r = 0; r < 4; r++)
            if (lx == 0) lsh[w * 32 + a * 16 + quad * 4 + r] = lred[a][r];
    }
    __syncthreads();
    {
        const size_t pbase = ((size_t)((kvh * BATCH + b) * NHEADS + h) * SEQ + q0);
        const int q    = t >> 1;
        const int half = t & 1;
        const float* prow = Po + (size_t)q * 68 + half * 32;
        float* dst = OP + (pbase + q) * HDIM + half * 32;
#pragma unroll
        for (int e = 0; e < 8; e++)
            ((float4*)dst)[e] = ((const float4*)prow)[e];
        if (t < 128) LP[pbase + t] = lsh[t];
    }
}

// ---------------------------------------------------------------------------
// Combine: OUT[b,s,h*64+d] = (O0 + O1) / (l0 + l1)
// ---------------------------------------------------------------------------
__global__ __launch_bounds__(256) void combine_kernel(
    const float* __restrict__ OP, const float* __restrict__ LP,
    float* __restrict__ OUT)
{
    const int idx = blockIdx.x * 256 + threadIdx.x;   // [b][s][h][d4]
    const int d4 = idx & 15;
    const int h  = (idx >> 4) & 15;
    const int s  = (idx >> 8) & (SEQ - 1);
    const int b  = idx >> 19;
    const size_t half_stride = (size_t)BATCH * NHEADS * SEQ;
    const size_t li = (size_t)(b * NHEADS + h) * SEQ + s;
    const size_t o0 = li * HDIM + d4 * 4;
    const float4 v0 = *(const float4*)(OP + o0);
    const float4 v1 = *(const float4*)(OP + o0 + half_stride * HDIM);
    const float inv = 1.f / (LP[li] + LP[li + half_stride]);
    float4 o;
    o.x = (v0.x + v1.x) * inv;
    o.y = (v0.y + v1.y) * inv;
    o.z = (v0.z + v1.z) * inv;
    o.w = (v0.w + v1.w) * inv;
    *(float4*)(OUT + ((size_t)(b * SEQ + s)) * HID + h * HDIM + d4 * 4) = o;
}

// ---------------------------------------------------------------------------
extern "C" void kernel_launch(void* const* d_in, const int* in_sizes, int n_in,
                              void* d_out, int out_size, void* d_ws, size_t ws_size,
                              hipStream_t stream)
{
    const float* X  = (const float*)d_in[0];
    const float* Wq = (const float*)d_in[1];
    const float* Wk = (const float*)d_in[2];
    const float* Wv = (const float*)d_in[3];
    float* out = (float*)d_out;

    const size_t qkv_elems = (size_t)BATCH * NHEADS * SEQ * HDIM;  // 4,194,304
    char* wsb = (char*)d_ws;
    float* ct  = (float*)wsb;                       // 0.5 MB
    float* st  = ct + (size_t)SEQ * HDIM;           // 0.5 MB
    u16* Xhi = (u16*)(st + (size_t)SEQ * HDIM);     // 8 MB
    u16* Xlo = Xhi + (size_t)NX;                    // 8 MB
    u16* Whi = Xlo + (size_t)NX;                    // 6 MB
    u16* Wlo = Whi + 3 * (size_t)NW;                // 6 MB
    u16* Qhi = Wlo + 3 * (size_t)NW;                // 8 MB
    u16* Qlo = Qhi + qkv_elems;                     // 8 MB
    u16* Khi = Qlo + qkv_elems;                     // 8 MB
    u16* Klo = Khi + qkv_elems;                     // 8 MB
    u16* Vhi = Klo + qkv_elems;                     // 8 MB
    u16* Vlo = Vhi + qkv_elems;                     // 8 MB
    float* OP = (float*)(Vlo + qkv_elems);          // 2 halves x 16.8 MB
    float* LP = OP + 2 * qkv_elems;                 // 2 halves x 0.26 MB
                                                    // total ~111.5 MB

    rope_tables_kernel<<<(SEQ * HDIM + 255) / 256, 256, 0, stream>>>(ct, st);

    const long tot = (long)NX + 3L * NW;
    split_kernel<<<(int)((tot / 4 + 255) / 256), 256, 0, stream>>>(
        X, Wq, Wk, Wv, Xhi, Xlo, Whi, Wlo);

    qkv_mfma_kernel<<<dim3(HID / 128, (BATCH * SEQ) / 128, 3), 256, 0, stream>>>(
        Xhi, Xlo, Whi, Wlo, ct, st, Qhi, Qlo, Khi, Klo, Vhi, Vlo);

    attn_kernel<<<dim3((SEQ / 128) * 2, NHEADS, BATCH), 256, 0, stream>>>(
        Qhi, Qlo, Khi, Klo, Vhi, Vlo, OP, LP);

    combine_kernel<<<(BATCH * SEQ * NHEADS * 16) / 256, 256, 0, stream>>>(
        OP, LP, out);
}

// Round 4
// 369.549 us; speedup vs baseline: 1.0514x; 1.0514x over previous
//
#include <hip/hip_runtime.h>
#include <math.h>

#define NHEADS 16
#define HDIM   64
#define HID    1024
#define BATCH  2
#define SEQ    2048
#define NX (BATCH*SEQ*HID)       // 4194304
#define NW (HID*HID)             // 1048576

typedef unsigned short u16;
typedef __attribute__((ext_vector_type(8))) short  bf16x8;   // 8 bf16 = 4 VGPR
typedef __attribute__((ext_vector_type(8))) unsigned short u16x8;
typedef __attribute__((ext_vector_type(4))) float  f32x4;

// ---------------------------------------------------------------------------
// Fragment-tiled layout ("FT"): operand rows r, inner dim k. Subtile =
// 16 rows x 32 k. Element (r,k) lives at
//   ((r>>4)*KB + (k>>5))*512 + ((k>>3)&3)*128 + (r&15)*8 + (k&7)     [u16]
// (KB = k-blocks per row-block row). A wave's MFMA fragment load
// (lane = quad*16+lx -> 16B) is then 64 lanes x 16B CONTIGUOUS: perfectly
// coalesced global_load_dwordx4, no LDS round-trip needed.
// hi / lo planes are separate arrays (keeps lane stride 16B).
// ---------------------------------------------------------------------------

__device__ __forceinline__ void split8(const float* xf, bf16x8& hi, bf16x8& lo) {
#pragma unroll
    for (int j = 0; j < 8; j++) {
        unsigned u = __float_as_uint(xf[j]);
        hi[j] = (short)(u >> 16);
        float hf = __uint_as_float(u & 0xFFFF0000u);
        lo[j] = (short)(__float_as_uint(xf[j] - hf) >> 16);
    }
}
__device__ __forceinline__ void split1(float v, u16& h, u16& l) {
    unsigned u = __float_as_uint(v);
    h = (u16)(u >> 16);
    l = (u16)(__float_as_uint(v - __uint_as_float(u & 0xFFFF0000u)) >> 16);
}

// ---------------------------------------------------------------------------
// RoPE tables
// ---------------------------------------------------------------------------
__global__ void rope_tables_kernel(float* __restrict__ ct, float* __restrict__ st) {
    int idx = blockIdx.x * 256 + threadIdx.x;
    if (idx >= SEQ * HDIM) return;
    int s  = idx >> 6;
    int dh = idx & 63;
    int i  = dh & 31;
    float inv = exp2f(-(float)i * (13.28771237954945f / 32.0f));  // log2(10000)/32
    float fr  = (float)s * inv;
    ct[idx] = cosf(fr);
    st[idx] = sinf(fr);
}

// ---------------------------------------------------------------------------
// Pre-pass: split X and W0/1/2 fp32 -> bf16 hi/lo planes, FRAG-TILED (KB=32).
// ---------------------------------------------------------------------------
__global__ void split_kernel(const float* __restrict__ X,
                             const float* __restrict__ W0,
                             const float* __restrict__ W1,
                             const float* __restrict__ W2,
                             u16* __restrict__ Xhi, u16* __restrict__ Xlo,
                             u16* __restrict__ Whi, u16* __restrict__ Wlo)
{
    long idx = ((long)blockIdx.x * 256 + threadIdx.x) * 4;
    if (idx >= (long)NX + 3L * NW) return;
    const float* src; u16* dh; u16* dl; long off;
    if (idx < NX) { src = X; dh = Xhi; dl = Xlo; off = idx; }
    else {
        long rr = idx - NX;
        int wi = (int)(rr >> 20);
        off = rr & (NW - 1);
        src = (wi == 0) ? W0 : ((wi == 1) ? W1 : W2);
        dh = Whi + (size_t)wi * NW;
        dl = Wlo + (size_t)wi * NW;
    }
    const int r = (int)(off >> 10);
    const int k = (int)(off & 1023);
    // frag-tiled offset (KB=32):
    const size_t fo = ((size_t)(r >> 4) * 32 + (k >> 5)) * 512
                    + (size_t)((k >> 3) & 3) * 128 + (size_t)(r & 15) * 8 + (k & 7);
    float4 v = *(const float4*)(src + off);
    const float* vf = (const float*)&v;
    ushort4 h4, l4;
    u16* hp = (u16*)&h4; u16* lp = (u16*)&l4;
#pragma unroll
    for (int e = 0; e < 4; e++) split1(vf[e], hp[e], lp[e]);
    *(ushort4*)(dh + fo) = h4;
    *(ushort4*)(dl + fo) = l4;
}

// ---------------------------------------------------------------------------
// MFMA QKV GEMM, NO LDS / NO BARRIERS in the K-loop: fragments loaded
// directly from frag-tiled global, register double-buffered.
// v5: 1D grid + XCD-ownership remap. HW round-robins linear block id across
// the 8 XCDs (id%8). Decompose so XCD x owns m-supertile x (4 m-panels x
// 8 n x 3 proj = 96 blocks): A-panels (2 MB) stay L2-resident (reused 24x),
// B-panels stream once per XCD. Cuts ~1.9 GB L3 re-fetch to ~110 MB.
// 128x128 block, 4 waves x 64x64, split-bf16 3-term emulation.
// Outputs (all frag-tiled, hi/lo planes, per (b,head) base = (b*16+h)*S*D):
//   proj 0: Q (RoPE, pre-scaled by log2(e)/8)  rows=s, k=dh, KB=2
//   proj 1: K (RoPE)  rows=s, k=dh, KB=2
//   proj 2: V^T       rows=d, k=s,  KB=64  (via LDS transpose in epilogue)
// ---------------------------------------------------------------------------
__global__ __launch_bounds__(256, 2) void qkv_mfma_kernel(
    const u16* __restrict__ Xhi, const u16* __restrict__ Xlo,
    const u16* __restrict__ Whi, const u16* __restrict__ Wlo,
    const float* __restrict__ ct, const float* __restrict__ st,
    u16* __restrict__ Qhi, u16* __restrict__ Qlo,
    u16* __restrict__ Khi, u16* __restrict__ Klo,
    u16* __restrict__ Vhi, u16* __restrict__ Vlo)
{
    __shared__ unsigned vtr[64][129];   // proj-2 transpose buffer only

    const int t    = threadIdx.x;
    const int lane = t & 63;
    const int w    = t >> 6;
    const int lx   = lane & 15;
    const int quad = lane >> 4;

    // XCD-ownership remap (768 blocks, 1D): xcd = lid%8 owns m-supertile xcd.
    // Within XCD: n fastest, then proj, then m_in.
    const int lid  = blockIdx.x;
    const int xcd  = lid & 7;
    const int i_   = lid >> 3;          // 0..95
    const int nb   = i_ & 7;
    const int j_   = i_ >> 3;           // 0..11
    const int proj = j_ % 3;
    const int mb   = xcd * 4 + j_ / 3;  // 0..31
    const int n0   = nb * 128;
    const int m0   = mb * 128;

    const u16* __restrict__ Wph = Whi + (size_t)proj * NW;
    const u16* __restrict__ Wpl = Wlo + (size_t)proj * NW;

    const int am = (w & 1) * 64;
    const int bn = (w >> 1) * 64;
    const int lp = quad * 128 + lx * 8;        // lane part of frag offset

    const u16 *pAh[4], *pAl[4], *pBh[4], *pBl[4];
#pragma unroll
    for (int i = 0; i < 4; i++) {
        const size_t o = ((size_t)(((m0 + am) >> 4) + i) * 32) * 512 + lp;
        pAh[i] = Xhi + o; pAl[i] = Xlo + o;
    }
#pragma unroll
    for (int j = 0; j < 4; j++) {
        const size_t o = ((size_t)(((n0 + bn) >> 4) + j) * 32) * 512 + lp;
        pBh[j] = Wph + o; pBl[j] = Wpl + o;
    }

    f32x4 acc[4][4];
#pragma unroll
    for (int i = 0; i < 4; i++)
#pragma unroll
        for (int j = 0; j < 4; j++) acc[i][j] = (f32x4){0.f, 0.f, 0.f, 0.f};

    // prefetch k-block 0
    bf16x8 cah[4], cal[4], cbh[4], cbl[4];
#pragma unroll
    for (int i = 0; i < 4; i++) { cah[i] = *(const bf16x8*)(pAh[i]); cal[i] = *(const bf16x8*)(pAl[i]); }
#pragma unroll
    for (int j = 0; j < 4; j++) { cbh[j] = *(const bf16x8*)(pBh[j]); cbl[j] = *(const bf16x8*)(pBl[j]); }

#pragma unroll 1
    for (int kt = 0; kt < HID; kt += 32) {
        const int ko = (kt + 32 < HID) ? ((kt + 32) >> 5) * 512 : 0;
        bf16x8 nah[4], nal[4], nbh[4], nbl[4];
#pragma unroll
        for (int i = 0; i < 4; i++) { nah[i] = *(const bf16x8*)(pAh[i] + ko); nal[i] = *(const bf16x8*)(pAl[i] + ko); }
#pragma unroll
        for (int j = 0; j < 4; j++) { nbh[j] = *(const bf16x8*)(pBh[j] + ko); nbl[j] = *(const bf16x8*)(pBl[j] + ko); }

#pragma unroll
        for (int j = 0; j < 4; j++)
#pragma unroll
            for (int i = 0; i < 4; i++) {
                acc[i][j] = __builtin_amdgcn_mfma_f32_16x16x32_bf16(cah[i], cbh[j], acc[i][j], 0, 0, 0);
                acc[i][j] = __builtin_amdgcn_mfma_f32_16x16x32_bf16(cal[i], cbh[j], acc[i][j], 0, 0, 0);
                acc[i][j] = __builtin_amdgcn_mfma_f32_16x16x32_bf16(cah[i], cbl[j], acc[i][j], 0, 0, 0);
            }
#pragma unroll
        for (int i = 0; i < 4; i++) { cah[i] = nah[i]; cal[i] = nal[i]; }
#pragma unroll
        for (int j = 0; j < 4; j++) { cbh[j] = nbh[j]; cbl[j] = nbl[j]; }
    }

    // ---- epilogue ----
    const int b      = m0 >> 11;
    const int head   = (n0 >> 6) + (w >> 1);
    const int m_base = m0 + am;

    if (proj < 2) {
        // RoPE in registers: partner dh^32 = acc[i][j^2], same lane.
#pragma unroll
        for (int i = 0; i < 4; i++) {
#pragma unroll
            for (int r = 0; r < 4; r++) {
                const int s = (m_base + i * 16 + quad * 4 + r) & 2047;
                const float* ctr = ct + s * HDIM;
                const float* str = st + s * HDIM;
                float nv[4];
#pragma unroll
                for (int j = 0; j < 4; j++) {
                    const int dh = j * 16 + lx;
                    const float c  = ctr[dh];
                    const float sn = str[dh];
                    const float x  = acc[i][j][r];
                    const float p  = acc[i][j ^ 2][r];
                    nv[j] = (j < 2) ? (x * c - p * sn) : (x * c + p * sn);
                }
#pragma unroll
                for (int j = 0; j < 4; j++) acc[i][j][r] = nv[j];
            }
        }
        // store Q or K, frag-tiled (rows=s, k=dh, KB=2)
        // Q additionally pre-scaled by log2(e)/8 so attn can exp2 directly.
        u16* dh_ = (proj == 0) ? Qhi : Khi;
        u16* dl_ = (proj == 0) ? Qlo : Klo;
        const float qscale = (proj == 0) ? 0.18033688011112042f : 1.0f;
        const size_t obase = (size_t)(b * NHEADS + head) * SEQ * HDIM;
#pragma unroll
        for (int i = 0; i < 4; i++)
#pragma unroll
            for (int r = 0; r < 4; r++) {
                const int s   = (m_base + i * 16 + quad * 4 + r) & 2047;
                const int rb  = s >> 4;
                const int lxq = s & 15;
#pragma unroll
                for (int j = 0; j < 4; j++) {
                    const size_t fo = obase + ((size_t)rb * 2 + (j >> 1)) * 512
                                    + (size_t)((j & 1) * 2 + (lx >> 3)) * 128
                                    + (size_t)lxq * 8 + (lx & 7);
                    u16 hh, ll;
                    split1(acc[i][j][r] * qscale, hh, ll);
                    dh_[fo] = hh;
                    dl_[fo] = ll;
                }
            }
    } else {
        // V: two-pass LDS transpose -> frag-tiled V^T (rows=d, k=s, KB=64)
#pragma unroll 1
        for (int pass = 0; pass < 2; pass++) {
            __syncthreads();
            if ((w & 1) == pass) {
#pragma unroll
                for (int i = 0; i < 4; i++)
#pragma unroll
                    for (int j = 0; j < 4; j++)
#pragma unroll
                        for (int r = 0; r < 4; r++) {
                            const int ml = i * 16 + quad * 4 + r;
                            const int nl = bn + j * 16 + lx;
                            const float v = acc[i][j][r];
                            unsigned u  = __float_as_uint(v);
                            unsigned hi = u & 0xFFFF0000u;
                            unsigned lo = __float_as_uint(v - __uint_as_float(hi)) >> 16;
                            vtr[ml][nl] = hi | lo;
                        }
            }
            __syncthreads();
            {
                const int d      = t >> 1;            // 0..127 (2 heads x 64)
                const int sh     = (t & 1) * 32;
                const int headv  = (n0 >> 6) + (d >> 6);
                const int dd     = d & 63;
                const size_t vbase = (size_t)(b * NHEADS + headv) * SEQ * HDIM;
                const int s0base = (m0 & 2047) + pass * 64 + sh;
#pragma unroll
                for (int k = 0; k < 4; k++) {
                    const int s0 = s0base + k * 8;
                    u16x8 hv, lv;
#pragma unroll
                    for (int e = 0; e < 8; e++) {
                        unsigned u = vtr[sh + k * 8 + e][d];
                        hv[e] = (u16)(u >> 16);
                        lv[e] = (u16)(u & 0xFFFFu);
                    }
                    const size_t fo = vbase + ((size_t)(dd >> 4) * 64 + (s0 >> 5)) * 512
                                    + (size_t)((s0 >> 3) & 3) * 128 + (size_t)(dd & 15) * 8;
                    *(u16x8*)(Vhi + fo) = hv;
                    *(u16x8*)(Vlo + fo) = lv;
                }
            }
        }
    }
}

// ---------------------------------------------------------------------------
// Flash attention, NO LDS for K/V (frag-tiled global loads), NO barriers in
// the tile loop. P round-trips per-wave LDS (wave-internal, lgkmcnt only).
// v5: round-2 structure (128-q blocks, register K double-buffer, V-early)
// PLUS XCD-ownership remap: 512 blocks 1D; XCD x owns 4 (b,h) heads
// (64 blocks) -> its 4 MB of K/V exactly fills one L2.
// Q arrives pre-scaled by log2(e)/8, so scores feed exp2 directly.
// ---------------------------------------------------------------------------
__global__ __launch_bounds__(256, 2) void attn_kernel(
    const u16* __restrict__ Qhi, const u16* __restrict__ Qlo,
    const u16* __restrict__ Khi, const u16* __restrict__ Klo,
    const u16* __restrict__ Vhi, const u16* __restrict__ Vlo,
    float* __restrict__ OUT)
{
    __shared__ float PS[4][32][68];

    const int t    = threadIdx.x;
    const int lane = t & 63;
    const int w    = t >> 6;
    const int lx   = lane & 15;
    const int quad = lane >> 4;

    // XCD-ownership remap (512 blocks, 1D): xcd = lid%8 owns 4 (b,h) heads.
    const int lid = blockIdx.x;
    const int xcd = lid & 7;
    const int i_  = lid >> 3;          // 0..63
    const int qx  = i_ & 15;
    const int bh  = xcd * 4 + (i_ >> 4); // 0..31
    const int h   = bh & 15;
    const int b   = bh >> 4;
    const int q0  = qx * 128;

    const size_t base = (size_t)(b * NHEADS + h) * SEQ * HDIM;
    const int lp = quad * 128 + lx * 8;

    // Q fragments (already split + pre-scaled in workspace)
    bf16x8 qh[2][2], ql[2][2];
#pragma unroll
    for (int a = 0; a < 2; a++)
#pragma unroll
        for (int ks = 0; ks < 2; ks++) {
            const size_t fo = base + ((size_t)((q0 >> 4) + w * 2 + a) * 2 + ks) * 512 + lp;
            qh[a][ks] = *(const bf16x8*)(Qhi + fo);
            ql[a][ks] = *(const bf16x8*)(Qlo + fo);
        }

    f32x4 O[2][4];
    float l_part[2][4];
#pragma unroll
    for (int a = 0; a < 2; a++) {
#pragma unroll
        for (int dt = 0; dt < 4; dt++) O[a][dt] = (f32x4){0.f,0.f,0.f,0.f};
#pragma unroll
        for (int r = 0; r < 4; r++) l_part[a][r] = 0.f;
    }

    // K double-buffer (A/B), prologue fills A with tile 0
    bf16x8 kAh[2][4], kAl[2][4], kBh[2][4], kBl[2][4];
#pragma unroll
    for (int c = 0; c < 4; c++)
#pragma unroll
        for (int ks = 0; ks < 2; ks++) {
            const size_t fo = base + ((size_t)c * 2 + ks) * 512 + lp;
            kAh[ks][c] = *(const bf16x8*)(Khi + fo);
            kAl[ks][c] = *(const bf16x8*)(Klo + fo);
        }

    // one kv-tile: consume (ckh,ckl) for tile kt, prefetch tile ktn into (nkh,nkl)
    auto tile_body = [&](bf16x8 (&ckh)[2][4], bf16x8 (&ckl)[2][4],
                         bf16x8 (&nkh)[2][4], bf16x8 (&nkl)[2][4],
                         int kt, int ktn) {
        // ---- V fragment loads (issued first; consumed after QK+exp) ----
        bf16x8 vh[2][4], vl[2][4];
#pragma unroll
        for (int dt = 0; dt < 4; dt++)
#pragma unroll
            for (int ks2 = 0; ks2 < 2; ks2++) {
                const size_t fo = base + ((size_t)dt * 64 + (kt >> 5) + ks2) * 512 + lp;
                vh[ks2][dt] = *(const bf16x8*)(Vhi + fo);
                vl[ks2][dt] = *(const bf16x8*)(Vlo + fo);
            }

        // ---- scores + exp -> PS (frees current K registers) ----
#pragma unroll
        for (int a = 0; a < 2; a++) {
#pragma unroll
            for (int c = 0; c < 4; c++) {
                f32x4 acc = (f32x4){0.f,0.f,0.f,0.f};
#pragma unroll
                for (int ks = 0; ks < 2; ks++) {
                    acc = __builtin_amdgcn_mfma_f32_16x16x32_bf16(qh[a][ks], ckh[ks][c], acc, 0, 0, 0);
                    acc = __builtin_amdgcn_mfma_f32_16x16x32_bf16(ql[a][ks], ckh[ks][c], acc, 0, 0, 0);
                    acc = __builtin_amdgcn_mfma_f32_16x16x32_bf16(qh[a][ks], ckl[ks][c], acc, 0, 0, 0);
                }
#pragma unroll
                for (int r = 0; r < 4; r++) {
                    float p = exp2f(acc[r]);           // Q pre-scaled: 2^(qk*log2e/8)
                    l_part[a][r] += p;
                    PS[w][a * 16 + quad * 4 + r][c * 16 + lx] = p;
                }
            }
        }

        // ---- prefetch next tile's K into alternate buffer ----
#pragma unroll
        for (int c = 0; c < 4; c++)
#pragma unroll
            for (int ks = 0; ks < 2; ks++) {
                const size_t fo = base + ((size_t)((ktn >> 4) + c) * 2 + ks) * 512 + lp;
                nkh[ks][c] = *(const bf16x8*)(Khi + fo);
                nkl[ks][c] = *(const bf16x8*)(Klo + fo);
            }

        // ---- PV ----
#pragma unroll
        for (int a = 0; a < 2; a++) {
#pragma unroll
            for (int ks2 = 0; ks2 < 2; ks2++) {
                const float* ps = &PS[w][a * 16 + lx][ks2 * 32 + quad * 8];
                float pf[8];
                *(float4*)&pf[0] = *(const float4*)ps;
                *(float4*)&pf[4] = *(const float4*)(ps + 4);
                bf16x8 phi, plo;
                split8(pf, phi, plo);
#pragma unroll
                for (int dt = 0; dt < 4; dt++) {
                    O[a][dt] = __builtin_amdgcn_mfma_f32_16x16x32_bf16(phi, vh[ks2][dt], O[a][dt], 0, 0, 0);
                    O[a][dt] = __builtin_amdgcn_mfma_f32_16x16x32_bf16(plo, vh[ks2][dt], O[a][dt], 0, 0, 0);
                    O[a][dt] = __builtin_amdgcn_mfma_f32_16x16x32_bf16(phi, vl[ks2][dt], O[a][dt], 0, 0, 0);
                }
            }
        }
    };

#pragma unroll 1
    for (int kt = 0; kt < SEQ; kt += 128) {
        tile_body(kAh, kAl, kBh, kBl, kt,       kt + 64);
        tile_body(kBh, kBl, kAh, kAl, kt + 64, (kt + 128) & (SEQ - 1));
    }

    float linv[2][4];
#pragma unroll
    for (int a = 0; a < 2; a++)
#pragma unroll
        for (int r = 0; r < 4; r++) {
            float l = l_part[a][r];
            l += __shfl_xor(l, 1);
            l += __shfl_xor(l, 2);
            l += __shfl_xor(l, 4);
            l += __shfl_xor(l, 8);
            linv[a][r] = 1.f / l;
        }

    float* Po = &PS[0][0][0];   // reuse as [128][68]
    __syncthreads();            // all waves done with their PS regions
#pragma unroll
    for (int a = 0; a < 2; a++)
#pragma unroll
        for (int dt = 0; dt < 4; dt++)
#pragma unroll
            for (int r = 0; r < 4; r++)
                Po[(size_t)(w * 32 + a * 16 + quad * 4 + r) * 68 + dt * 16 + lx] =
                    O[a][dt][r] * linv[a][r];
    __syncthreads();
    {
        const int q    = t >> 1;
        const int half = t & 1;
        const float* prow = Po + (size_t)q * 68 + half * 32;
        float* dst = OUT + ((size_t)(b * SEQ + q0 + q)) * HID + h * HDIM + half * 32;
#pragma unroll
        for (int e = 0; e < 8; e++)
            ((float4*)dst)[e] = ((const float4*)prow)[e];
    }
}

// ---------------------------------------------------------------------------
extern "C" void kernel_launch(void* const* d_in, const int* in_sizes, int n_in,
                              void* d_out, int out_size, void* d_ws, size_t ws_size,
                              hipStream_t stream)
{
    const float* X  = (const float*)d_in[0];
    const float* Wq = (const float*)d_in[1];
    const float* Wk = (const float*)d_in[2];
    const float* Wv = (const float*)d_in[3];
    float* out = (float*)d_out;

    const size_t qkv_elems = (size_t)BATCH * NHEADS * SEQ * HDIM;  // 4,194,304
    char* wsb = (char*)d_ws;
    float* ct  = (float*)wsb;                       // 0.5 MB
    float* st  = ct + (size_t)SEQ * HDIM;           // 0.5 MB
    u16* Xhi = (u16*)(st + (size_t)SEQ * HDIM);     // 8 MB
    u16* Xlo = Xhi + (size_t)NX;                    // 8 MB
    u16* Whi = Xlo + (size_t)NX;                    // 6 MB
    u16* Wlo = Whi + 3 * (size_t)NW;                // 6 MB
    u16* Qhi = Wlo + 3 * (size_t)NW;                // 8 MB
    u16* Qlo = Qhi + qkv_elems;                     // 8 MB
    u16* Khi = Qlo + qkv_elems;                     // 8 MB
    u16* Klo = Khi + qkv_elems;                     // 8 MB
    u16* Vhi = Klo + qkv_elems;                     // 8 MB
    u16* Vlo = Vhi + qkv_elems;                     // 8 MB   (total 77 MB)

    rope_tables_kernel<<<(SEQ * HDIM + 255) / 256, 256, 0, stream>>>(ct, st);

    const long tot = (long)NX + 3L * NW;
    split_kernel<<<(int)((tot / 4 + 255) / 256), 256, 0, stream>>>(
        X, Wq, Wk, Wv, Xhi, Xlo, Whi, Wlo);

    qkv_mfma_kernel<<<dim3(3 * (HID / 128) * ((BATCH * SEQ) / 128)), 256, 0, stream>>>(
        Xhi, Xlo, Whi, Wlo, ct, st, Qhi, Qlo, Khi, Klo, Vhi, Vlo);

    attn_kernel<<<dim3((SEQ / 128) * NHEADS * BATCH), 256, 0, stream>>>(
        Qhi, Qlo, Khi, Klo, Vhi, Vlo, out);
}

// Round 5
// 305.210 us; speedup vs baseline: 1.2731x; 1.2108x over previous
//
#include <hip/hip_runtime.h>
#include <math.h>

#define NHEADS 16
#define HDIM   64
#define HID    1024
#define BATCH  2
#define SEQ    2048
#define NX (BATCH*SEQ*HID)       // 4194304
#define NW (HID*HID)             // 1048576

typedef unsigned short u16;
typedef __attribute__((ext_vector_type(8))) short  bf16x8;   // 8 bf16 = 4 VGPR
typedef __attribute__((ext_vector_type(8))) unsigned short u16x8;
typedef __attribute__((ext_vector_type(4))) float  f32x4;

// ---------------------------------------------------------------------------
// Fragment-tiled layout ("FT"): operand rows r, inner dim k. Subtile =
// 16 rows x 32 k. Element (r,k) lives at
//   ((r>>4)*KB + (k>>5))*512 + ((k>>3)&3)*128 + (r&15)*8 + (k&7)     [u16]
// (KB = k-blocks per row-block row). A wave's MFMA fragment load
// (lane = quad*16+lx -> 16B) is then 64 lanes x 16B CONTIGUOUS: perfectly
// coalesced global_load_dwordx4, no LDS round-trip needed.
// hi / lo planes are separate arrays (keeps lane stride 16B).
// ---------------------------------------------------------------------------

__device__ __forceinline__ void split8(const float* xf, bf16x8& hi, bf16x8& lo) {
#pragma unroll
    for (int j = 0; j < 8; j++) {
        unsigned u = __float_as_uint(xf[j]);
        hi[j] = (short)(u >> 16);
        float hf = __uint_as_float(u & 0xFFFF0000u);
        lo[j] = (short)(__float_as_uint(xf[j] - hf) >> 16);
    }
}
__device__ __forceinline__ void split1(float v, u16& h, u16& l) {
    unsigned u = __float_as_uint(v);
    h = (u16)(u >> 16);
    l = (u16)(__float_as_uint(v - __uint_as_float(u & 0xFFFF0000u)) >> 16);
}

// ---------------------------------------------------------------------------
// RoPE tables
// ---------------------------------------------------------------------------
__global__ void rope_tables_kernel(float* __restrict__ ct, float* __restrict__ st) {
    int idx = blockIdx.x * 256 + threadIdx.x;
    if (idx >= SEQ * HDIM) return;
    int s  = idx >> 6;
    int dh = idx & 63;
    int i  = dh & 31;
    float inv = exp2f(-(float)i * (13.28771237954945f / 32.0f));  // log2(10000)/32
    float fr  = (float)s * inv;
    ct[idx] = cosf(fr);
    st[idx] = sinf(fr);
}

// ---------------------------------------------------------------------------
// Pre-pass: split X and W0/1/2 fp32 -> bf16 hi/lo planes, FRAG-TILED (KB=32).
// ---------------------------------------------------------------------------
__global__ void split_kernel(const float* __restrict__ X,
                             const float* __restrict__ W0,
                             const float* __restrict__ W1,
                             const float* __restrict__ W2,
                             u16* __restrict__ Xhi, u16* __restrict__ Xlo,
                             u16* __restrict__ Whi, u16* __restrict__ Wlo)
{
    long idx = ((long)blockIdx.x * 256 + threadIdx.x) * 4;
    if (idx >= (long)NX + 3L * NW) return;
    const float* src; u16* dh; u16* dl; long off;
    if (idx < NX) { src = X; dh = Xhi; dl = Xlo; off = idx; }
    else {
        long rr = idx - NX;
        int wi = (int)(rr >> 20);
        off = rr & (NW - 1);
        src = (wi == 0) ? W0 : ((wi == 1) ? W1 : W2);
        dh = Whi + (size_t)wi * NW;
        dl = Wlo + (size_t)wi * NW;
    }
    const int r = (int)(off >> 10);
    const int k = (int)(off & 1023);
    // frag-tiled offset (KB=32):
    const size_t fo = ((size_t)(r >> 4) * 32 + (k >> 5)) * 512
                    + (size_t)((k >> 3) & 3) * 128 + (size_t)(r & 15) * 8 + (k & 7);
    float4 v = *(const float4*)(src + off);
    const float* vf = (const float*)&v;
    ushort4 h4, l4;
    u16* hp = (u16*)&h4; u16* lp = (u16*)&l4;
#pragma unroll
    for (int e = 0; e < 4; e++) split1(vf[e], hp[e], lp[e]);
    *(ushort4*)(dh + fo) = h4;
    *(ushort4*)(dl + fo) = l4;
}

// ---------------------------------------------------------------------------
// MFMA QKV GEMM, NO LDS / NO BARRIERS in the K-loop: fragments loaded
// directly from frag-tiled global, register double-buffered.
// v6: XCD remap with N-OWNERSHIP. xcd = lid%8 (HW round-robin) = nb: the
// XCD's resident set is its 3 B-panels (n-slice of Wq/Wk/Wv, 1.5 MB) which
// stay L2-resident; A (X) streams once per XCD with its 3 proj uses
// temporally adjacent (proj fastest, then mb). Round-4's m-ownership failed
// because the concurrent working set (12 MB of B) overflowed L2.
// 128x128 block, 4 waves x 64x64, split-bf16 3-term emulation.
// Outputs (all frag-tiled, hi/lo planes, per (b,head) base = (b*16+h)*S*D):
//   proj 0: Q (RoPE, pre-scaled by log2(e)/8)  rows=s, k=dh, KB=2
//   proj 1: K (RoPE)  rows=s, k=dh, KB=2
//   proj 2: V^T       rows=d, k=s,  KB=64  (via LDS transpose in epilogue)
// ---------------------------------------------------------------------------
__global__ __launch_bounds__(256, 2) void qkv_mfma_kernel(
    const u16* __restrict__ Xhi, const u16* __restrict__ Xlo,
    const u16* __restrict__ Whi, const u16* __restrict__ Wlo,
    const float* __restrict__ ct, const float* __restrict__ st,
    u16* __restrict__ Qhi, u16* __restrict__ Qlo,
    u16* __restrict__ Khi, u16* __restrict__ Klo,
    u16* __restrict__ Vhi, u16* __restrict__ Vlo)
{
    __shared__ unsigned vtr[64][129];   // proj-2 transpose buffer only

    const int t    = threadIdx.x;
    const int lane = t & 63;
    const int w    = t >> 6;
    const int lx   = lane & 15;
    const int quad = lane >> 4;

    // XCD n-ownership remap (768 blocks, 1D): xcd = lid%8 owns n-panel xcd.
    // Within XCD: proj fastest, then mb (A panel's 3 proj uses adjacent).
    const int lid  = blockIdx.x;
    const int xcd  = lid & 7;
    const int i_   = lid >> 3;          // 0..95
    const int proj = i_ % 3;
    const int mb   = i_ / 3;            // 0..31
    const int nb   = xcd;
    const int n0   = nb * 128;
    const int m0   = mb * 128;

    const u16* __restrict__ Wph = Whi + (size_t)proj * NW;
    const u16* __restrict__ Wpl = Wlo + (size_t)proj * NW;

    const int am = (w & 1) * 64;
    const int bn = (w >> 1) * 64;
    const int lp = quad * 128 + lx * 8;        // lane part of frag offset

    const u16 *pAh[4], *pAl[4], *pBh[4], *pBl[4];
#pragma unroll
    for (int i = 0; i < 4; i++) {
        const size_t o = ((size_t)(((m0 + am) >> 4) + i) * 32) * 512 + lp;
        pAh[i] = Xhi + o; pAl[i] = Xlo + o;
    }
#pragma unroll
    for (int j = 0; j < 4; j++) {
        const size_t o = ((size_t)(((n0 + bn) >> 4) + j) * 32) * 512 + lp;
        pBh[j] = Wph + o; pBl[j] = Wpl + o;
    }

    f32x4 acc[4][4];
#pragma unroll
    for (int i = 0; i < 4; i++)
#pragma unroll
        for (int j = 0; j < 4; j++) acc[i][j] = (f32x4){0.f, 0.f, 0.f, 0.f};

    // prefetch k-block 0
    bf16x8 cah[4], cal[4], cbh[4], cbl[4];
#pragma unroll
    for (int i = 0; i < 4; i++) { cah[i] = *(const bf16x8*)(pAh[i]); cal[i] = *(const bf16x8*)(pAl[i]); }
#pragma unroll
    for (int j = 0; j < 4; j++) { cbh[j] = *(const bf16x8*)(pBh[j]); cbl[j] = *(const bf16x8*)(pBl[j]); }

#pragma unroll 1
    for (int kt = 0; kt < HID; kt += 32) {
        const int ko = (kt + 32 < HID) ? ((kt + 32) >> 5) * 512 : 0;
        bf16x8 nah[4], nal[4], nbh[4], nbl[4];
#pragma unroll
        for (int i = 0; i < 4; i++) { nah[i] = *(const bf16x8*)(pAh[i] + ko); nal[i] = *(const bf16x8*)(pAl[i] + ko); }
#pragma unroll
        for (int j = 0; j < 4; j++) { nbh[j] = *(const bf16x8*)(pBh[j] + ko); nbl[j] = *(const bf16x8*)(pBl[j] + ko); }

#pragma unroll
        for (int j = 0; j < 4; j++)
#pragma unroll
            for (int i = 0; i < 4; i++) {
                acc[i][j] = __builtin_amdgcn_mfma_f32_16x16x32_bf16(cah[i], cbh[j], acc[i][j], 0, 0, 0);
                acc[i][j] = __builtin_amdgcn_mfma_f32_16x16x32_bf16(cal[i], cbh[j], acc[i][j], 0, 0, 0);
                acc[i][j] = __builtin_amdgcn_mfma_f32_16x16x32_bf16(cah[i], cbl[j], acc[i][j], 0, 0, 0);
            }
#pragma unroll
        for (int i = 0; i < 4; i++) { cah[i] = nah[i]; cal[i] = nal[i]; }
#pragma unroll
        for (int j = 0; j < 4; j++) { cbh[j] = nbh[j]; cbl[j] = nbl[j]; }
    }

    // ---- epilogue ----
    const int b      = m0 >> 11;
    const int head   = (n0 >> 6) + (w >> 1);
    const int m_base = m0 + am;

    if (proj < 2) {
        // RoPE in registers: partner dh^32 = acc[i][j^2], same lane.
#pragma unroll
        for (int i = 0; i < 4; i++) {
#pragma unroll
            for (int r = 0; r < 4; r++) {
                const int s = (m_base + i * 16 + quad * 4 + r) & 2047;
                const float* ctr = ct + s * HDIM;
                const float* str = st + s * HDIM;
                float nv[4];
#pragma unroll
                for (int j = 0; j < 4; j++) {
                    const int dh = j * 16 + lx;
                    const float c  = ctr[dh];
                    const float sn = str[dh];
                    const float x  = acc[i][j][r];
                    const float p  = acc[i][j ^ 2][r];
                    nv[j] = (j < 2) ? (x * c - p * sn) : (x * c + p * sn);
                }
#pragma unroll
                for (int j = 0; j < 4; j++) acc[i][j][r] = nv[j];
            }
        }
        // store Q or K, frag-tiled (rows=s, k=dh, KB=2)
        // Q additionally pre-scaled by log2(e)/8 so attn can exp2 directly.
        u16* dh_ = (proj == 0) ? Qhi : Khi;
        u16* dl_ = (proj == 0) ? Qlo : Klo;
        const float qscale = (proj == 0) ? 0.18033688011112042f : 1.0f;
        const size_t obase = (size_t)(b * NHEADS + head) * SEQ * HDIM;
#pragma unroll
        for (int i = 0; i < 4; i++)
#pragma unroll
            for (int r = 0; r < 4; r++) {
                const int s   = (m_base + i * 16 + quad * 4 + r) & 2047;
                const int rb  = s >> 4;
                const int lxq = s & 15;
#pragma unroll
                for (int j = 0; j < 4; j++) {
                    const size_t fo = obase + ((size_t)rb * 2 + (j >> 1)) * 512
                                    + (size_t)((j & 1) * 2 + (lx >> 3)) * 128
                                    + (size_t)lxq * 8 + (lx & 7);
                    u16 hh, ll;
                    split1(acc[i][j][r] * qscale, hh, ll);
                    dh_[fo] = hh;
                    dl_[fo] = ll;
                }
            }
    } else {
        // V: two-pass LDS transpose -> frag-tiled V^T (rows=d, k=s, KB=64)
#pragma unroll 1
        for (int pass = 0; pass < 2; pass++) {
            __syncthreads();
            if ((w & 1) == pass) {
#pragma unroll
                for (int i = 0; i < 4; i++)
#pragma unroll
                    for (int j = 0; j < 4; j++)
#pragma unroll
                        for (int r = 0; r < 4; r++) {
                            const int ml = i * 16 + quad * 4 + r;
                            const int nl = bn + j * 16 + lx;
                            const float v = acc[i][j][r];
                            unsigned u  = __float_as_uint(v);
                            unsigned hi = u & 0xFFFF0000u;
                            unsigned lo = __float_as_uint(v - __uint_as_float(hi)) >> 16;
                            vtr[ml][nl] = hi | lo;
                        }
            }
            __syncthreads();
            {
                const int d      = t >> 1;            // 0..127 (2 heads x 64)
                const int sh     = (t & 1) * 32;
                const int headv  = (n0 >> 6) + (d >> 6);
                const int dd     = d & 63;
                const size_t vbase = (size_t)(b * NHEADS + headv) * SEQ * HDIM;
                const int s0base = (m0 & 2047) + pass * 64 + sh;
#pragma unroll
                for (int k = 0; k < 4; k++) {
                    const int s0 = s0base + k * 8;
                    u16x8 hv, lv;
#pragma unroll
                    for (int e = 0; e < 8; e++) {
                        unsigned u = vtr[sh + k * 8 + e][d];
                        hv[e] = (u16)(u >> 16);
                        lv[e] = (u16)(u & 0xFFFFu);
                    }
                    const size_t fo = vbase + ((size_t)(dd >> 4) * 64 + (s0 >> 5)) * 512
                                    + (size_t)((s0 >> 3) & 3) * 128 + (size_t)(dd & 15) * 8;
                    *(u16x8*)(Vhi + fo) = hv;
                    *(u16x8*)(Vlo + fo) = lv;
                }
            }
        }
    }
}

// ---------------------------------------------------------------------------
// Flash attention, NO LDS for K/V (frag-tiled global loads), NO barriers in
// the tile loop. P round-trips per-wave LDS (wave-internal, lgkmcnt only).
// EXACT round-2 form (141 us, VGPR 128): 128-q blocks, 3D grid, register
// K double-buffer, V-early software pipeline.
// Q arrives pre-scaled by log2(e)/8, so scores feed exp2 directly.
// ---------------------------------------------------------------------------
__global__ __launch_bounds__(256, 2) void attn_kernel(
    const u16* __restrict__ Qhi, const u16* __restrict__ Qlo,
    const u16* __restrict__ Khi, const u16* __restrict__ Klo,
    const u16* __restrict__ Vhi, const u16* __restrict__ Vlo,
    float* __restrict__ OUT)
{
    __shared__ float PS[4][32][68];

    const int t    = threadIdx.x;
    const int lane = t & 63;
    const int w    = t >> 6;
    const int lx   = lane & 15;
    const int quad = lane >> 4;

    const int q0 = blockIdx.x * 128;
    const int h  = blockIdx.y;
    const int b  = blockIdx.z;
    const size_t base = (size_t)(b * NHEADS + h) * SEQ * HDIM;
    const int lp = quad * 128 + lx * 8;

    // Q fragments (already split + pre-scaled in workspace)
    bf16x8 qh[2][2], ql[2][2];
#pragma unroll
    for (int a = 0; a < 2; a++)
#pragma unroll
        for (int ks = 0; ks < 2; ks++) {
            const size_t fo = base + ((size_t)((q0 >> 4) + w * 2 + a) * 2 + ks) * 512 + lp;
            qh[a][ks] = *(const bf16x8*)(Qhi + fo);
            ql[a][ks] = *(const bf16x8*)(Qlo + fo);
        }

    f32x4 O[2][4];
    float l_part[2][4];
#pragma unroll
    for (int a = 0; a < 2; a++) {
#pragma unroll
        for (int dt = 0; dt < 4; dt++) O[a][dt] = (f32x4){0.f,0.f,0.f,0.f};
#pragma unroll
        for (int r = 0; r < 4; r++) l_part[a][r] = 0.f;
    }

    // K double-buffer (A/B), prologue fills A with tile 0
    bf16x8 kAh[2][4], kAl[2][4], kBh[2][4], kBl[2][4];
#pragma unroll
    for (int c = 0; c < 4; c++)
#pragma unroll
        for (int ks = 0; ks < 2; ks++) {
            const size_t fo = base + ((size_t)c * 2 + ks) * 512 + lp;
            kAh[ks][c] = *(const bf16x8*)(Khi + fo);
            kAl[ks][c] = *(const bf16x8*)(Klo + fo);
        }

    // one kv-tile: consume (ckh,ckl) for tile kt, prefetch tile ktn into (nkh,nkl)
    auto tile_body = [&](bf16x8 (&ckh)[2][4], bf16x8 (&ckl)[2][4],
                         bf16x8 (&nkh)[2][4], bf16x8 (&nkl)[2][4],
                         int kt, int ktn) {
        // ---- V fragment loads (issued first; consumed after QK+exp) ----
        bf16x8 vh[2][4], vl[2][4];
#pragma unroll
        for (int dt = 0; dt < 4; dt++)
#pragma unroll
            for (int ks2 = 0; ks2 < 2; ks2++) {
                const size_t fo = base + ((size_t)dt * 64 + (kt >> 5) + ks2) * 512 + lp;
                vh[ks2][dt] = *(const bf16x8*)(Vhi + fo);
                vl[ks2][dt] = *(const bf16x8*)(Vlo + fo);
            }

        // ---- scores + exp -> PS (frees current K registers) ----
#pragma unroll
        for (int a = 0; a < 2; a++) {
#pragma unroll
            for (int c = 0; c < 4; c++) {
                f32x4 acc = (f32x4){0.f,0.f,0.f,0.f};
#pragma unroll
                for (int ks = 0; ks < 2; ks++) {
                    acc = __builtin_amdgcn_mfma_f32_16x16x32_bf16(qh[a][ks], ckh[ks][c], acc, 0, 0, 0);
                    acc = __builtin_amdgcn_mfma_f32_16x16x32_bf16(ql[a][ks], ckh[ks][c], acc, 0, 0, 0);
                    acc = __builtin_amdgcn_mfma_f32_16x16x32_bf16(qh[a][ks], ckl[ks][c], acc, 0, 0, 0);
                }
#pragma unroll
                for (int r = 0; r < 4; r++) {
                    float p = exp2f(acc[r]);           // Q pre-scaled: 2^(qk*log2e/8)
                    l_part[a][r] += p;
                    PS[w][a * 16 + quad * 4 + r][c * 16 + lx] = p;
                }
            }
        }

        // ---- prefetch next tile's K into alternate buffer ----
#pragma unroll
        for (int c = 0; c < 4; c++)
#pragma unroll
            for (int ks = 0; ks < 2; ks++) {
                const size_t fo = base + ((size_t)((ktn >> 4) + c) * 2 + ks) * 512 + lp;
                nkh[ks][c] = *(const bf16x8*)(Khi + fo);
                nkl[ks][c] = *(const bf16x8*)(Klo + fo);
            }

        // ---- PV ----
#pragma unroll
        for (int a = 0; a < 2; a++) {
#pragma unroll
            for (int ks2 = 0; ks2 < 2; ks2++) {
                const float* ps = &PS[w][a * 16 + lx][ks2 * 32 + quad * 8];
                float pf[8];
                *(float4*)&pf[0] = *(const float4*)ps;
                *(float4*)&pf[4] = *(const float4*)(ps + 4);
                bf16x8 phi, plo;
                split8(pf, phi, plo);
#pragma unroll
                for (int dt = 0; dt < 4; dt++) {
                    O[a][dt] = __builtin_amdgcn_mfma_f32_16x16x32_bf16(phi, vh[ks2][dt], O[a][dt], 0, 0, 0);
                    O[a][dt] = __builtin_amdgcn_mfma_f32_16x16x32_bf16(plo, vh[ks2][dt], O[a][dt], 0, 0, 0);
                    O[a][dt] = __builtin_amdgcn_mfma_f32_16x16x32_bf16(phi, vl[ks2][dt], O[a][dt], 0, 0, 0);
                }
            }
        }
    };

#pragma unroll 1
    for (int kt = 0; kt < SEQ; kt += 128) {
        tile_body(kAh, kAl, kBh, kBl, kt,       kt + 64);
        tile_body(kBh, kBl, kAh, kAl, kt + 64, (kt + 128) & (SEQ - 1));
    }

    float linv[2][4];
#pragma unroll
    for (int a = 0; a < 2; a++)
#pragma unroll
        for (int r = 0; r < 4; r++) {
            float l = l_part[a][r];
            l += __shfl_xor(l, 1);
            l += __shfl_xor(l, 2);
            l += __shfl_xor(l, 4);
            l += __shfl_xor(l, 8);
            linv[a][r] = 1.f / l;
        }

    float* Po = &PS[0][0][0];   // reuse as [128][68]
    __syncthreads();            // all waves done with their PS regions
#pragma unroll
    for (int a = 0; a < 2; a++)
#pragma unroll
        for (int dt = 0; dt < 4; dt++)
#pragma unroll
            for (int r = 0; r < 4; r++)
                Po[(size_t)(w * 32 + a * 16 + quad * 4 + r) * 68 + dt * 16 + lx] =
                    O[a][dt][r] * linv[a][r];
    __syncthreads();
    {
        const int q    = t >> 1;
        const int half = t & 1;
        const float* prow = Po + (size_t)q * 68 + half * 32;
        float* dst = OUT + ((size_t)(b * SEQ + q0 + q)) * HID + h * HDIM + half * 32;
#pragma unroll
        for (int e = 0; e < 8; e++)
            ((float4*)dst)[e] = ((const float4*)prow)[e];
    }
}

// ---------------------------------------------------------------------------
extern "C" void kernel_launch(void* const* d_in, const int* in_sizes, int n_in,
                              void* d_out, int out_size, void* d_ws, size_t ws_size,
                              hipStream_t stream)
{
    const float* X  = (const float*)d_in[0];
    const float* Wq = (const float*)d_in[1];
    const float* Wk = (const float*)d_in[2];
    const float* Wv = (const float*)d_in[3];
    float* out = (float*)d_out;

    const size_t qkv_elems = (size_t)BATCH * NHEADS * SEQ * HDIM;  // 4,194,304
    char* wsb = (char*)d_ws;
    float* ct  = (float*)wsb;                       // 0.5 MB
    float* st  = ct + (size_t)SEQ * HDIM;           // 0.5 MB
    u16* Xhi = (u16*)(st + (size_t)SEQ * HDIM);     // 8 MB
    u16* Xlo = Xhi + (size_t)NX;                    // 8 MB
    u16* Whi = Xlo + (size_t)NX;                    // 6 MB
    u16* Wlo = Whi + 3 * (size_t)NW;                // 6 MB
    u16* Qhi = Wlo + 3 * (size_t)NW;                // 8 MB
    u16* Qlo = Qhi + qkv_elems;                     // 8 MB
    u16* Khi = Qlo + qkv_elems;                     // 8 MB
    u16* Klo = Khi + qkv_elems;                     // 8 MB
    u16* Vhi = Klo + qkv_elems;                     // 8 MB
    u16* Vlo = Vhi + qkv_elems;                     // 8 MB   (total 77 MB)

    rope_tables_kernel<<<(SEQ * HDIM + 255) / 256, 256, 0, stream>>>(ct, st);

    const long tot = (long)NX + 3L * NW;
    split_kernel<<<(int)((tot / 4 + 255) / 256), 256, 0, stream>>>(
        X, Wq, Wk, Wv, Xhi, Xlo, Whi, Wlo);

    qkv_mfma_kernel<<<dim3(3 * (HID / 128) * ((BATCH * SEQ) / 128)), 256, 0, stream>>>(
        Xhi, Xlo, Whi, Wlo, ct, st, Qhi, Qlo, Khi, Klo, Vhi, Vlo);

    attn_kernel<<<dim3(SEQ / 128, NHEADS, BATCH), 256, 0, stream>>>(
        Qhi, Qlo, Khi, Klo, Vhi, Vlo, out);
}

// Round 6
// 304.049 us; speedup vs baseline: 1.2780x; 1.0038x over previous
//
#include <hip/hip_runtime.h>
#include <math.h>

#define NHEADS 16
#define HDIM   64
#define HID    1024
#define BATCH  2
#define SEQ    2048
#define NX (BATCH*SEQ*HID)       // 4194304
#define NW (HID*HID)             // 1048576

typedef unsigned short u16;
typedef __attribute__((ext_vector_type(8))) short  bf16x8;   // 8 bf16 = 4 VGPR
typedef __attribute__((ext_vector_type(8))) unsigned short u16x8;
typedef __attribute__((ext_vector_type(4))) float  f32x4;

// ---------------------------------------------------------------------------
// Fragment-tiled layout ("FT"): operand rows r, inner dim k. Subtile =
// 16 rows x 32 k. Element (r,k) lives at
//   ((r>>4)*KB + (k>>5))*512 + ((k>>3)&3)*128 + (r&15)*8 + (k&7)     [u16]
// (KB = k-blocks per row-block row). A wave's MFMA fragment load
// (lane = quad*16+lx -> 16B) is then 64 lanes x 16B CONTIGUOUS: perfectly
// coalesced global_load_dwordx4, no LDS round-trip needed.
// hi / lo planes are separate arrays (keeps lane stride 16B).
// ---------------------------------------------------------------------------

// v_perm-based split: hi pair = bytes[2,3] of each fp32 (truncated bf16),
// lo pair = bytes[2,3] of (p - hi) — numerically identical to shift form,
// 24 VALU ops per call instead of ~48 (split8 was ~half of attn's VALU).
__device__ __forceinline__ void split8(const float* xf, bf16x8& hi, bf16x8& lo) {
    unsigned* hp = (unsigned*)&hi;
    unsigned* lp = (unsigned*)&lo;
#pragma unroll
    for (int j = 0; j < 4; j++) {
        const float p0 = xf[2 * j], p1 = xf[2 * j + 1];
        const unsigned u0 = __float_as_uint(p0);
        const unsigned u1 = __float_as_uint(p1);
        hp[j] = __builtin_amdgcn_perm(u1, u0, 0x07060302u);
        const float l0 = p0 - __uint_as_float(u0 & 0xFFFF0000u);
        const float l1 = p1 - __uint_as_float(u1 & 0xFFFF0000u);
        lp[j] = __builtin_amdgcn_perm(__float_as_uint(l1), __float_as_uint(l0), 0x07060302u);
    }
}
__device__ __forceinline__ void split1(float v, u16& h, u16& l) {
    unsigned u = __float_as_uint(v);
    h = (u16)(u >> 16);
    l = (u16)(__float_as_uint(v - __uint_as_float(u & 0xFFFF0000u)) >> 16);
}

// ---------------------------------------------------------------------------
// RoPE tables
// ---------------------------------------------------------------------------
__global__ void rope_tables_kernel(float* __restrict__ ct, float* __restrict__ st) {
    int idx = blockIdx.x * 256 + threadIdx.x;
    if (idx >= SEQ * HDIM) return;
    int s  = idx >> 6;
    int dh = idx & 63;
    int i  = dh & 31;
    float inv = exp2f(-(float)i * (13.28771237954945f / 32.0f));  // log2(10000)/32
    float fr  = (float)s * inv;
    ct[idx] = cosf(fr);
    st[idx] = sinf(fr);
}

// ---------------------------------------------------------------------------
// Pre-pass: split X and W0/1/2 fp32 -> bf16 hi/lo planes, FRAG-TILED (KB=32).
// ---------------------------------------------------------------------------
__global__ void split_kernel(const float* __restrict__ X,
                             const float* __restrict__ W0,
                             const float* __restrict__ W1,
                             const float* __restrict__ W2,
                             u16* __restrict__ Xhi, u16* __restrict__ Xlo,
                             u16* __restrict__ Whi, u16* __restrict__ Wlo)
{
    long idx = ((long)blockIdx.x * 256 + threadIdx.x) * 4;
    if (idx >= (long)NX + 3L * NW) return;
    const float* src; u16* dh; u16* dl; long off;
    if (idx < NX) { src = X; dh = Xhi; dl = Xlo; off = idx; }
    else {
        long rr = idx - NX;
        int wi = (int)(rr >> 20);
        off = rr & (NW - 1);
        src = (wi == 0) ? W0 : ((wi == 1) ? W1 : W2);
        dh = Whi + (size_t)wi * NW;
        dl = Wlo + (size_t)wi * NW;
    }
    const int r = (int)(off >> 10);
    const int k = (int)(off & 1023);
    // frag-tiled offset (KB=32):
    const size_t fo = ((size_t)(r >> 4) * 32 + (k >> 5)) * 512
                    + (size_t)((k >> 3) & 3) * 128 + (size_t)(r & 15) * 8 + (k & 7);
    float4 v = *(const float4*)(src + off);
    const float* vf = (const float*)&v;
    ushort4 h4, l4;
    u16* hp = (u16*)&h4; u16* lp = (u16*)&l4;
#pragma unroll
    for (int e = 0; e < 4; e++) split1(vf[e], hp[e], lp[e]);
    *(ushort4*)(dh + fo) = h4;
    *(ushort4*)(dl + fo) = l4;
}

// ---------------------------------------------------------------------------
// MFMA QKV GEMM, NO LDS / NO BARRIERS in the K-loop: fragments loaded
// directly from frag-tiled global, register double-buffered.
// v7: XCD n-ownership remap (kept from v6) + manual 2x-unrolled K-loop with
// buffer ROLE SWAP (kills 64 v_mov/step of buffer copies) + s_setprio
// around the MFMA clusters (waves are barrier-free/independent).
// 128x128 block, 4 waves x 64x64, split-bf16 3-term emulation.
// Outputs (all frag-tiled, hi/lo planes, per (b,head) base = (b*16+h)*S*D):
//   proj 0: Q (RoPE, pre-scaled by log2(e)/8)  rows=s, k=dh, KB=2
//   proj 1: K (RoPE)  rows=s, k=dh, KB=2
//   proj 2: V^T       rows=d, k=s,  KB=64  (via LDS transpose in epilogue)
// ---------------------------------------------------------------------------
__global__ __launch_bounds__(256, 2) void qkv_mfma_kernel(
    const u16* __restrict__ Xhi, const u16* __restrict__ Xlo,
    const u16* __restrict__ Whi, const u16* __restrict__ Wlo,
    const float* __restrict__ ct, const float* __restrict__ st,
    u16* __restrict__ Qhi, u16* __restrict__ Qlo,
    u16* __restrict__ Khi, u16* __restrict__ Klo,
    u16* __restrict__ Vhi, u16* __restrict__ Vlo)
{
    __shared__ unsigned vtr[64][129];   // proj-2 transpose buffer only

    const int t    = threadIdx.x;
    const int lane = t & 63;
    const int w    = t >> 6;
    const int lx   = lane & 15;
    const int quad = lane >> 4;

    // XCD n-ownership remap (768 blocks, 1D): xcd = lid%8 owns n-panel xcd.
    // Within XCD: proj fastest, then mb (A panel's 3 proj uses adjacent).
    const int lid  = blockIdx.x;
    const int xcd  = lid & 7;
    const int i_   = lid >> 3;          // 0..95
    const int proj = i_ % 3;
    const int mb   = i_ / 3;            // 0..31
    const int nb   = xcd;
    const int n0   = nb * 128;
    const int m0   = mb * 128;

    const u16* __restrict__ Wph = Whi + (size_t)proj * NW;
    const u16* __restrict__ Wpl = Wlo + (size_t)proj * NW;

    const int am = (w & 1) * 64;
    const int bn = (w >> 1) * 64;
    const int lp = quad * 128 + lx * 8;        // lane part of frag offset

    const u16 *pAh[4], *pAl[4], *pBh[4], *pBl[4];
#pragma unroll
    for (int i = 0; i < 4; i++) {
        const size_t o = ((size_t)(((m0 + am) >> 4) + i) * 32) * 512 + lp;
        pAh[i] = Xhi + o; pAl[i] = Xlo + o;
    }
#pragma unroll
    for (int j = 0; j < 4; j++) {
        const size_t o = ((size_t)(((n0 + bn) >> 4) + j) * 32) * 512 + lp;
        pBh[j] = Wph + o; pBl[j] = Wpl + o;
    }

    f32x4 acc[4][4];
#pragma unroll
    for (int i = 0; i < 4; i++)
#pragma unroll
        for (int j = 0; j < 4; j++) acc[i][j] = (f32x4){0.f, 0.f, 0.f, 0.f};

    bf16x8 cah[4], cal[4], cbh[4], cbl[4];
    bf16x8 nah[4], nal[4], nbh[4], nbl[4];
    // prefetch k-block 0 into c-buffers
#pragma unroll
    for (int i = 0; i < 4; i++) { cah[i] = *(const bf16x8*)(pAh[i]); cal[i] = *(const bf16x8*)(pAl[i]); }
#pragma unroll
    for (int j = 0; j < 4; j++) { cbh[j] = *(const bf16x8*)(pBh[j]); cbl[j] = *(const bf16x8*)(pBl[j]); }

#pragma unroll 1
    for (int kt = 0; kt < HID; kt += 64) {
        const int ko1 = ((kt + 32) >> 5) * 512;                         // kt+32 < HID always
        const int ko2 = (kt + 64 < HID) ? ((kt + 64) >> 5) * 512 : 0;   // wrap (harmless)

        // prefetch k-block kt+32 into n-buffers
#pragma unroll
        for (int i = 0; i < 4; i++) { nah[i] = *(const bf16x8*)(pAh[i] + ko1); nal[i] = *(const bf16x8*)(pAl[i] + ko1); }
#pragma unroll
        for (int j = 0; j < 4; j++) { nbh[j] = *(const bf16x8*)(pBh[j] + ko1); nbl[j] = *(const bf16x8*)(pBl[j] + ko1); }

        __builtin_amdgcn_s_setprio(1);
#pragma unroll
        for (int j = 0; j < 4; j++)
#pragma unroll
            for (int i = 0; i < 4; i++) {
                acc[i][j] = __builtin_amdgcn_mfma_f32_16x16x32_bf16(cah[i], cbh[j], acc[i][j], 0, 0, 0);
                acc[i][j] = __builtin_amdgcn_mfma_f32_16x16x32_bf16(cal[i], cbh[j], acc[i][j], 0, 0, 0);
                acc[i][j] = __builtin_amdgcn_mfma_f32_16x16x32_bf16(cah[i], cbl[j], acc[i][j], 0, 0, 0);
            }
        __builtin_amdgcn_s_setprio(0);

        // prefetch k-block kt+64 into c-buffers
#pragma unroll
        for (int i = 0; i < 4; i++) { cah[i] = *(const bf16x8*)(pAh[i] + ko2); cal[i] = *(const bf16x8*)(pAl[i] + ko2); }
#pragma unroll
        for (int j = 0; j < 4; j++) { cbh[j] = *(const bf16x8*)(pBh[j] + ko2); cbl[j] = *(const bf16x8*)(pBl[j] + ko2); }

        __builtin_amdgcn_s_setprio(1);
#pragma unroll
        for (int j = 0; j < 4; j++)
#pragma unroll
            for (int i = 0; i < 4; i++) {
                acc[i][j] = __builtin_amdgcn_mfma_f32_16x16x32_bf16(nah[i], nbh[j], acc[i][j], 0, 0, 0);
                acc[i][j] = __builtin_amdgcn_mfma_f32_16x16x32_bf16(nal[i], nbh[j], acc[i][j], 0, 0, 0);
                acc[i][j] = __builtin_amdgcn_mfma_f32_16x16x32_bf16(nah[i], nbl[j], acc[i][j], 0, 0, 0);
            }
        __builtin_amdgcn_s_setprio(0);
    }

    // ---- epilogue ----
    const int b      = m0 >> 11;
    const int head   = (n0 >> 6) + (w >> 1);
    const int m_base = m0 + am;

    if (proj < 2) {
        // RoPE in registers: partner dh^32 = acc[i][j^2], same lane.
#pragma unroll
        for (int i = 0; i < 4; i++) {
#pragma unroll
            for (int r = 0; r < 4; r++) {
                const int s = (m_base + i * 16 + quad * 4 + r) & 2047;
                const float* ctr = ct + s * HDIM;
                const float* str = st + s * HDIM;
                float nv[4];
#pragma unroll
                for (int j = 0; j < 4; j++) {
                    const int dh = j * 16 + lx;
                    const float c  = ctr[dh];
                    const float sn = str[dh];
                    const float x  = acc[i][j][r];
                    const float p  = acc[i][j ^ 2][r];
                    nv[j] = (j < 2) ? (x * c - p * sn) : (x * c + p * sn);
                }
#pragma unroll
                for (int j = 0; j < 4; j++) acc[i][j][r] = nv[j];
            }
        }
        // store Q or K, frag-tiled (rows=s, k=dh, KB=2)
        // Q additionally pre-scaled by log2(e)/8 so attn can exp2 directly.
        u16* dh_ = (proj == 0) ? Qhi : Khi;
        u16* dl_ = (proj == 0) ? Qlo : Klo;
        const float qscale = (proj == 0) ? 0.18033688011112042f : 1.0f;
        const size_t obase = (size_t)(b * NHEADS + head) * SEQ * HDIM;
#pragma unroll
        for (int i = 0; i < 4; i++)
#pragma unroll
            for (int r = 0; r < 4; r++) {
                const int s   = (m_base + i * 16 + quad * 4 + r) & 2047;
                const int rb  = s >> 4;
                const int lxq = s & 15;
#pragma unroll
                for (int j = 0; j < 4; j++) {
                    const size_t fo = obase + ((size_t)rb * 2 + (j >> 1)) * 512
                                    + (size_t)((j & 1) * 2 + (lx >> 3)) * 128
                                    + (size_t)lxq * 8 + (lx & 7);
                    u16 hh, ll;
                    split1(acc[i][j][r] * qscale, hh, ll);
                    dh_[fo] = hh;
                    dl_[fo] = ll;
                }
            }
    } else {
        // V: two-pass LDS transpose -> frag-tiled V^T (rows=d, k=s, KB=64)
#pragma unroll 1
        for (int pass = 0; pass < 2; pass++) {
            __syncthreads();
            if ((w & 1) == pass) {
#pragma unroll
                for (int i = 0; i < 4; i++)
#pragma unroll
                    for (int j = 0; j < 4; j++)
#pragma unroll
                        for (int r = 0; r < 4; r++) {
                            const int ml = i * 16 + quad * 4 + r;
                            const int nl = bn + j * 16 + lx;
                            const float v = acc[i][j][r];
                            unsigned u  = __float_as_uint(v);
                            unsigned hi = u & 0xFFFF0000u;
                            unsigned lo = __float_as_uint(v - __uint_as_float(hi)) >> 16;
                            vtr[ml][nl] = hi | lo;
                        }
            }
            __syncthreads();
            {
                const int d      = t >> 1;            // 0..127 (2 heads x 64)
                const int sh     = (t & 1) * 32;
                const int headv  = (n0 >> 6) + (d >> 6);
                const int dd     = d & 63;
                const size_t vbase = (size_t)(b * NHEADS + headv) * SEQ * HDIM;
                const int s0base = (m0 & 2047) + pass * 64 + sh;
#pragma unroll
                for (int k = 0; k < 4; k++) {
                    const int s0 = s0base + k * 8;
                    u16x8 hv, lv;
#pragma unroll
                    for (int e = 0; e < 8; e++) {
                        unsigned u = vtr[sh + k * 8 + e][d];
                        hv[e] = (u16)(u >> 16);
                        lv[e] = (u16)(u & 0xFFFFu);
                    }
                    const size_t fo = vbase + ((size_t)(dd >> 4) * 64 + (s0 >> 5)) * 512
                                    + (size_t)((s0 >> 3) & 3) * 128 + (size_t)(dd & 15) * 8;
                    *(u16x8*)(Vhi + fo) = hv;
                    *(u16x8*)(Vlo + fo) = lv;
                }
            }
        }
    }
}

// ---------------------------------------------------------------------------
// Flash attention, NO LDS for K/V (frag-tiled global loads), NO barriers in
// the tile loop. P round-trips per-wave LDS (wave-internal, lgkmcnt only).
// Round-2 structure (128-q blocks, 3D grid, register K double-buffer,
// V-early pipeline) + perm-based split8 + s_setprio around MFMA clusters.
// Q arrives pre-scaled by log2(e)/8, so scores feed exp2 directly.
// ---------------------------------------------------------------------------
__global__ __launch_bounds__(256, 2) void attn_kernel(
    const u16* __restrict__ Qhi, const u16* __restrict__ Qlo,
    const u16* __restrict__ Khi, const u16* __restrict__ Klo,
    const u16* __restrict__ Vhi, const u16* __restrict__ Vlo,
    float* __restrict__ OUT)
{
    __shared__ float PS[4][32][68];

    const int t    = threadIdx.x;
    const int lane = t & 63;
    const int w    = t >> 6;
    const int lx   = lane & 15;
    const int quad = lane >> 4;

    const int q0 = blockIdx.x * 128;
    const int h  = blockIdx.y;
    const int b  = blockIdx.z;
    const size_t base = (size_t)(b * NHEADS + h) * SEQ * HDIM;
    const int lp = quad * 128 + lx * 8;

    // Q fragments (already split + pre-scaled in workspace)
    bf16x8 qh[2][2], ql[2][2];
#pragma unroll
    for (int a = 0; a < 2; a++)
#pragma unroll
        for (int ks = 0; ks < 2; ks++) {
            const size_t fo = base + ((size_t)((q0 >> 4) + w * 2 + a) * 2 + ks) * 512 + lp;
            qh[a][ks] = *(const bf16x8*)(Qhi + fo);
            ql[a][ks] = *(const bf16x8*)(Qlo + fo);
        }

    f32x4 O[2][4];
    float l_part[2][4];
#pragma unroll
    for (int a = 0; a < 2; a++) {
#pragma unroll
        for (int dt = 0; dt < 4; dt++) O[a][dt] = (f32x4){0.f,0.f,0.f,0.f};
#pragma unroll
        for (int r = 0; r < 4; r++) l_part[a][r] = 0.f;
    }

    // K double-buffer (A/B), prologue fills A with tile 0
    bf16x8 kAh[2][4], kAl[2][4], kBh[2][4], kBl[2][4];
#pragma unroll
    for (int c = 0; c < 4; c++)
#pragma unroll
        for (int ks = 0; ks < 2; ks++) {
            const size_t fo = base + ((size_t)c * 2 + ks) * 512 + lp;
            kAh[ks][c] = *(const bf16x8*)(Khi + fo);
            kAl[ks][c] = *(const bf16x8*)(Klo + fo);
        }

    // one kv-tile: consume (ckh,ckl) for tile kt, prefetch tile ktn into (nkh,nkl)
    auto tile_body = [&](bf16x8 (&ckh)[2][4], bf16x8 (&ckl)[2][4],
                         bf16x8 (&nkh)[2][4], bf16x8 (&nkl)[2][4],
                         int kt, int ktn) {
        // ---- V fragment loads (issued first; consumed after QK+exp) ----
        bf16x8 vh[2][4], vl[2][4];
#pragma unroll
        for (int dt = 0; dt < 4; dt++)
#pragma unroll
            for (int ks2 = 0; ks2 < 2; ks2++) {
                const size_t fo = base + ((size_t)dt * 64 + (kt >> 5) + ks2) * 512 + lp;
                vh[ks2][dt] = *(const bf16x8*)(Vhi + fo);
                vl[ks2][dt] = *(const bf16x8*)(Vlo + fo);
            }

        // ---- scores + exp -> PS (frees current K registers) ----
#pragma unroll
        for (int a = 0; a < 2; a++) {
#pragma unroll
            for (int c = 0; c < 4; c++) {
                f32x4 acc = (f32x4){0.f,0.f,0.f,0.f};
                __builtin_amdgcn_s_setprio(1);
#pragma unroll
                for (int ks = 0; ks < 2; ks++) {
                    acc = __builtin_amdgcn_mfma_f32_16x16x32_bf16(qh[a][ks], ckh[ks][c], acc, 0, 0, 0);
                    acc = __builtin_amdgcn_mfma_f32_16x16x32_bf16(ql[a][ks], ckh[ks][c], acc, 0, 0, 0);
                    acc = __builtin_amdgcn_mfma_f32_16x16x32_bf16(qh[a][ks], ckl[ks][c], acc, 0, 0, 0);
                }
                __builtin_amdgcn_s_setprio(0);
#pragma unroll
                for (int r = 0; r < 4; r++) {
                    float p = exp2f(acc[r]);           // Q pre-scaled: 2^(qk*log2e/8)
                    l_part[a][r] += p;
                    PS[w][a * 16 + quad * 4 + r][c * 16 + lx] = p;
                }
            }
        }

        // ---- prefetch next tile's K into alternate buffer ----
#pragma unroll
        for (int c = 0; c < 4; c++)
#pragma unroll
            for (int ks = 0; ks < 2; ks++) {
                const size_t fo = base + ((size_t)((ktn >> 4) + c) * 2 + ks) * 512 + lp;
                nkh[ks][c] = *(const bf16x8*)(Khi + fo);
                nkl[ks][c] = *(const bf16x8*)(Klo + fo);
            }

        // ---- PV ----
#pragma unroll
        for (int a = 0; a < 2; a++) {
#pragma unroll
            for (int ks2 = 0; ks2 < 2; ks2++) {
                const float* ps = &PS[w][a * 16 + lx][ks2 * 32 + quad * 8];
                float pf[8];
                *(float4*)&pf[0] = *(const float4*)ps;
                *(float4*)&pf[4] = *(const float4*)(ps + 4);
                bf16x8 phi, plo;
                split8(pf, phi, plo);
                __builtin_amdgcn_s_setprio(1);
#pragma unroll
                for (int dt = 0; dt < 4; dt++) {
                    O[a][dt] = __builtin_amdgcn_mfma_f32_16x16x32_bf16(phi, vh[ks2][dt], O[a][dt], 0, 0, 0);
                    O[a][dt] = __builtin_amdgcn_mfma_f32_16x16x32_bf16(plo, vh[ks2][dt], O[a][dt], 0, 0, 0);
                    O[a][dt] = __builtin_amdgcn_mfma_f32_16x16x32_bf16(phi, vl[ks2][dt], O[a][dt], 0, 0, 0);
                }
                __builtin_amdgcn_s_setprio(0);
            }
        }
    };

#pragma unroll 1
    for (int kt = 0; kt < SEQ; kt += 128) {
        tile_body(kAh, kAl, kBh, kBl, kt,       kt + 64);
        tile_body(kBh, kBl, kAh, kAl, kt + 64, (kt + 128) & (SEQ - 1));
    }

    float linv[2][4];
#pragma unroll
    for (int a = 0; a < 2; a++)
#pragma unroll
        for (int r = 0; r < 4; r++) {
            float l = l_part[a][r];
            l += __shfl_xor(l, 1);
            l += __shfl_xor(l, 2);
            l += __shfl_xor(l, 4);
            l += __shfl_xor(l, 8);
            linv[a][r] = 1.f / l;
        }

    float* Po = &PS[0][0][0];   // reuse as [128][68]
    __syncthreads();            // all waves done with their PS regions
#pragma unroll
    for (int a = 0; a < 2; a++)
#pragma unroll
        for (int dt = 0; dt < 4; dt++)
#pragma unroll
            for (int r = 0; r < 4; r++)
                Po[(size_t)(w * 32 + a * 16 + quad * 4 + r) * 68 + dt * 16 + lx] =
                    O[a][dt][r] * linv[a][r];
    __syncthreads();
    {
        const int q    = t >> 1;
        const int half = t & 1;
        const float* prow = Po + (size_t)q * 68 + half * 32;
        float* dst = OUT + ((size_t)(b * SEQ + q0 + q)) * HID + h * HDIM + half * 32;
#pragma unroll
        for (int e = 0; e < 8; e++)
            ((float4*)dst)[e] = ((const float4*)prow)[e];
    }
}

// ---------------------------------------------------------------------------
extern "C" void kernel_launch(void* const* d_in, const int* in_sizes, int n_in,
                              void* d_out, int out_size, void* d_ws, size_t ws_size,
                              hipStream_t stream)
{
    const float* X  = (const float*)d_in[0];
    const float* Wq = (const float*)d_in[1];
    const float* Wk = (const float*)d_in[2];
    const float* Wv = (const float*)d_in[3];
    float* out = (float*)d_out;

    const size_t qkv_elems = (size_t)BATCH * NHEADS * SEQ * HDIM;  // 4,194,304
    char* wsb = (char*)d_ws;
    float* ct  = (float*)wsb;                       // 0.5 MB
    float* st  = ct + (size_t)SEQ * HDIM;           // 0.5 MB
    u16* Xhi = (u16*)(st + (size_t)SEQ * HDIM);     // 8 MB
    u16* Xlo = Xhi + (size_t)NX;                    // 8 MB
    u16* Whi = Xlo + (size_t)NX;                    // 6 MB
    u16* Wlo = Whi + 3 * (size_t)NW;                // 6 MB
    u16* Qhi = Wlo + 3 * (size_t)NW;                // 8 MB
    u16* Qlo = Qhi + qkv_elems;                     // 8 MB
    u16* Khi = Qlo + qkv_elems;                     // 8 MB
    u16* Klo = Khi + qkv_elems;                     // 8 MB
    u16* Vhi = Klo + qkv_elems;                     // 8 MB
    u16* Vlo = Vhi + qkv_elems;                     // 8 MB   (total 77 MB)

    rope_tables_kernel<<<(SEQ * HDIM + 255) / 256, 256, 0, stream>>>(ct, st);

    const long tot = (long)NX + 3L * NW;
    split_kernel<<<(int)((tot / 4 + 255) / 256), 256, 0, stream>>>(
        X, Wq, Wk, Wv, Xhi, Xlo, Whi, Wlo);

    qkv_mfma_kernel<<<dim3(3 * (HID / 128) * ((BATCH * SEQ) / 128)), 256, 0, stream>>>(
        Xhi, Xlo, Whi, Wlo, ct, st, Qhi, Qlo, Khi, Klo, Vhi, Vlo);

    attn_kernel<<<dim3(SEQ / 128, NHEADS, BATCH), 256, 0, stream>>>(
        Qhi, Qlo, Khi, Klo, Vhi, Vlo, out);
}